// Round 6
// baseline (1186.729 us; speedup 1.0000x reference)
//
#include <hip/hip_runtime.h>
#include <hip/hip_bf16.h>
#include <hip/hip_cooperative_groups.h>

namespace cg = cooperative_groups;

// NodeModel fused GNN block, round 6.
// Structure (proven rounds 4-5) + launch-count reduction:
//   [coop]  prep weights + zero + hist + parallel scan + scatter  (1 launch)
//   y     = x @ W1a[0:128] + b1a                       (bf16)
//   TMP[pose[e]] = bf16(relu(y[row_e] + EA[e]@W1a[128:192]))   (E)
//   mean  = contiguous segment sum / max(cnt,1)                 (R)
//   out   = relu(x@W2c + mean@W2d + b2a + gate*bc + vtab[batch]) @ W2b + b2b
//           (h1 and out GEMMs fused via per-wave LDS transpose)

typedef __bf16 bf16x8 __attribute__((ext_vector_type(8)));
typedef float f32x4v __attribute__((ext_vector_type(4)));

#define NN 40000
#define NE 640000

__device__ inline bf16x8 cvt8(const float* __restrict__ p) {
  f32x4v a = *(const f32x4v*)p;
  f32x4v b = *(const f32x4v*)(p + 4);
  bf16x8 r;
  r[0] = (__bf16)a[0]; r[1] = (__bf16)a[1]; r[2] = (__bf16)a[2]; r[3] = (__bf16)a[3];
  r[4] = (__bf16)b[0]; r[5] = (__bf16)b[1]; r[6] = (__bf16)b[2]; r[7] = (__bf16)b[3];
  return r;
}

// ======================= cooperative prep + sort ============================
__global__ __launch_bounds__(256) void coop_prep_sort(
    const float* __restrict__ W1a, const float* __restrict__ W2a,
    const float* __restrict__ W2b, const float* __restrict__ W1b,
    const float* __restrict__ b1b, const float* __restrict__ u,
    const int* __restrict__ EI,
    __bf16* __restrict__ WTya, __bf16* __restrict__ WTeb,
    __bf16* __restrict__ WT2c, __bf16* __restrict__ WT2bT,
    __bf16* __restrict__ WT2d, float* __restrict__ vtab,
    float* __restrict__ bc,
    int* __restrict__ cnt, int* __restrict__ offs,
    int* __restrict__ bsum, int* __restrict__ pose)
{
  cg::grid_group grid = cg::this_grid();
  __shared__ int sc[256];
  int tid = blockIdx.x * 256 + threadIdx.x;
  int nth = gridDim.x * 256;

  // P0: weight transposes / folds + zero cnt
  for (int i = tid; i < 16384; i += nth) {
    int n = i & 127, k = i >> 7;
    WTya[n * 128 + k] = (__bf16)W1a[k * 128 + n];
  }
  for (int i = tid; i < 8192; i += nth) {
    int n = i & 127, k = i >> 7;
    WTeb[n * 64 + k] = (__bf16)W1a[(128 + k) * 128 + n];
  }
  for (int i = tid; i < 16384; i += nth) {
    int n = i & 127, k = i >> 7;
    WT2c[n * 128 + k] = (__bf16)W2a[k * 128 + n];
  }
  for (int i = tid; i < 16384; i += nth) {
    int n = i & 127, k = i >> 7;
    WT2bT[n * 128 + k] = (__bf16)W2b[k * 128 + n];
  }
  for (int i = tid; i < 8192; i += nth) {
    int n = i & 127, g = i >> 7;
    float s = 0.f;
    for (int k = 0; k < 64; ++k) s += u[g * 64 + k] * W2a[(256 + k) * 128 + n];
    vtab[g * 128 + n] = s;
  }
  for (int i = tid; i < 128; i += nth) {
    float s = 0.f;
    for (int j = 0; j < 128; ++j) s += b1b[j] * W2a[(128 + j) * 128 + i];
    bc[i] = s;
  }
  for (int i = tid; i < 16384; i += nth) {
    int n = i & 127, k = i >> 7;
    float s = 0.f;
    for (int j = 0; j < 128; ++j) s += W1b[k * 128 + j] * W2a[(128 + j) * 128 + n];
    WT2d[n * 128 + k] = (__bf16)s;
  }
  for (int i = tid; i < NN; i += nth) cnt[i] = 0;
  grid.sync();

  // P1: histogram
  for (int e = tid; e < NE; e += nth) atomicAdd(&cnt[EI[NE + e]], 1);
  grid.sync();

  // P2: block-level exclusive scan (157 blocks x 256)
  if (blockIdx.x < 157) {
    int i = blockIdx.x * 256 + threadIdx.x;
    int v = (i < NN) ? cnt[i] : 0;
    sc[threadIdx.x] = v;
    __syncthreads();
    for (int off = 1; off < 256; off <<= 1) {
      int t2 = (threadIdx.x >= off) ? sc[threadIdx.x - off] : 0;
      __syncthreads();
      sc[threadIdx.x] += t2;
      __syncthreads();
    }
    if (i < NN) offs[i] = sc[threadIdx.x] - v;
    if (threadIdx.x == 255) bsum[blockIdx.x] = sc[255];
  }
  grid.sync();

  // P3: scan of 157 block sums (block 0)
  if (blockIdx.x == 0) {
    int v = (threadIdx.x < 157) ? bsum[threadIdx.x] : 0;
    sc[threadIdx.x] = v;
    __syncthreads();
    for (int off = 1; off < 256; off <<= 1) {
      int t2 = (threadIdx.x >= off) ? sc[threadIdx.x - off] : 0;
      __syncthreads();
      sc[threadIdx.x] += t2;
      __syncthreads();
    }
    if (threadIdx.x < 157) bsum[threadIdx.x] = sc[threadIdx.x] - v;
  }
  grid.sync();

  // P4: add block bases -> global exclusive prefix
  for (int i = tid; i < NN; i += nth) offs[i] += bsum[i >> 8];
  grid.sync();

  // P5: scatter -> pose[e]; offs mutates to END offsets (node_R contract)
  for (int e = tid; e < NE; e += nth)
    pose[e] = atomicAdd(&offs[EI[NE + e]], 1);
}

// ======================= fallback (non-cooperative) sort ====================
__global__ __launch_bounds__(256) void fb_prep(
    const float* __restrict__ W1a, const float* __restrict__ W2a,
    const float* __restrict__ W2b, const float* __restrict__ W1b,
    const float* __restrict__ b1b, const float* __restrict__ u,
    __bf16* __restrict__ WTya, __bf16* __restrict__ WTeb,
    __bf16* __restrict__ WT2c, __bf16* __restrict__ WT2bT,
    __bf16* __restrict__ WT2d, float* __restrict__ vtab,
    float* __restrict__ bc)
{
  int b = blockIdx.x, t = threadIdx.x;
  if (b < 64) {
    int idx = b * 256 + t; int n = idx & 127; int k = idx >> 7;
    WTya[n * 128 + k] = (__bf16)W1a[k * 128 + n];
  } else if (b < 96) {
    int idx = (b - 64) * 256 + t; int n = idx & 127; int k = idx >> 7;
    WTeb[n * 64 + k] = (__bf16)W1a[(128 + k) * 128 + n];
  } else if (b < 160) {
    int idx = (b - 96) * 256 + t; int n = idx & 127; int k = idx >> 7;
    WT2c[n * 128 + k] = (__bf16)W2a[k * 128 + n];
  } else if (b < 224) {
    int idx = (b - 160) * 256 + t; int n = idx & 127; int k = idx >> 7;
    WT2bT[n * 128 + k] = (__bf16)W2b[k * 128 + n];
  } else if (b < 256) {
    int idx = (b - 224) * 256 + t; int n = idx & 127; int gi = idx >> 7;
    float s = 0.f;
    for (int k = 0; k < 64; ++k) s += u[gi * 64 + k] * W2a[(256 + k) * 128 + n];
    vtab[gi * 128 + n] = s;
  } else if (b == 256) {
    if (t < 128) {
      float s = 0.f;
      for (int j = 0; j < 128; ++j) s += b1b[j] * W2a[(128 + j) * 128 + t];
      bc[t] = s;
    }
  } else {
    int k = b - 257;
    if (t < 128) {
      float s = 0.f;
      for (int j = 0; j < 128; ++j) s += W1b[k * 128 + j] * W2a[(128 + j) * 128 + t];
      WT2d[t * 128 + k] = (__bf16)s;
    }
  }
}

__global__ __launch_bounds__(256) void fb_hist(const int* __restrict__ EI,
                                               int* __restrict__ cnt) {
  int e = blockIdx.x * 256 + threadIdx.x;
  atomicAdd(&cnt[EI[NE + e]], 1);
}

__global__ __launch_bounds__(1024) void fb_scan(const int* __restrict__ cnt,
                                                int* __restrict__ offs) {
  __shared__ int part[1024];
  int t = threadIdx.x;
  int base = t * 40;
  int s = 0;
  for (int k = 0; k < 40; ++k) { int idx = base + k; if (idx < NN) s += cnt[idx]; }
  part[t] = s;
  __syncthreads();
  for (int off = 1; off < 1024; off <<= 1) {
    int v = (t >= off) ? part[t - off] : 0;
    __syncthreads();
    part[t] += v;
    __syncthreads();
  }
  int pre = part[t] - s;
  for (int k = 0; k < 40; ++k) {
    int idx = base + k;
    if (idx < NN) { offs[idx] = pre; pre += cnt[idx]; }
  }
}

__global__ __launch_bounds__(256) void fb_scatter(const int* __restrict__ EI,
                                                  int* __restrict__ offs,
                                                  int* __restrict__ pose) {
  int e = blockIdx.x * 256 + threadIdx.x;
  pose[e] = atomicAdd(&offs[EI[NE + e]], 1);
}

// ======================= y-GEMM: Yb = bf16(x @ WTya^T + b1a) ================
__global__ __launch_bounds__(256) void gemm_y(
    const float* __restrict__ x, const __bf16* __restrict__ WTya,
    const float* __restrict__ b1a, __bf16* __restrict__ Yb)
{
  int lane = threadIdx.x & 63;
  int wave = threadIdx.x >> 6;
  int rowbase = blockIdx.x * 64 + wave * 16;
  int g = lane >> 4, c = lane & 15;

  f32x4v acc[8];
#pragma unroll
  for (int nt = 0; nt < 8; ++nt) acc[nt] = (f32x4v)(0.f);

  const float* arow = x + (size_t)(rowbase + c) * 128;
#pragma unroll
  for (int kk = 0; kk < 128; kk += 32) {
    bf16x8 af = cvt8(arow + kk + g * 8);
#pragma unroll
    for (int nt = 0; nt < 8; ++nt) {
      bf16x8 bf = *(const bf16x8*)(WTya + (nt * 16 + c) * 128 + kk + g * 8);
      acc[nt] = __builtin_amdgcn_mfma_f32_16x16x32_bf16(af, bf, acc[nt], 0, 0, 0);
    }
  }
#pragma unroll
  for (int q = 0; q < 4; ++q) {
    int r = rowbase + g * 4 + q;
#pragma unroll
    for (int nt = 0; nt < 8; ++nt) {
      int n = nt * 16 + c;
      Yb[(size_t)r * 128 + n] = (__bf16)(acc[nt][q] + b1a[n]);
    }
  }
}

// ======================= E: edge GEMM, scattered sorted store ===============
__global__ __launch_bounds__(256) void edge_E(
    const float* __restrict__ EA, const int* __restrict__ EI,
    const int* __restrict__ pose, const __bf16* __restrict__ WTeb,
    const __bf16* __restrict__ Yb, __bf16* __restrict__ TMP)
{
  __shared__ __bf16 vb16[64 * 136];
  __shared__ int lrow[64], lpos[64];
  int t = threadIdx.x;
  int i0 = blockIdx.x * 64;
  if (t < 64) {
    lrow[t] = EI[i0 + t];
    lpos[t] = pose[i0 + t];
  }
  __syncthreads();

  int lane = t & 63, w = t >> 6, g = lane >> 4, c = lane & 15;
  f32x4v acc[8];
#pragma unroll
  for (int nt = 0; nt < 8; ++nt) acc[nt] = (f32x4v)(0.f);

  const float* arow = EA + (size_t)(i0 + w * 16 + c) * 64;
#pragma unroll
  for (int kk = 0; kk < 64; kk += 32) {
    bf16x8 af = cvt8(arow + kk + g * 8);
#pragma unroll
    for (int nt = 0; nt < 8; ++nt) {
      bf16x8 bf = *(const bf16x8*)(WTeb + (nt * 16 + c) * 64 + kk + g * 8);
      acc[nt] = __builtin_amdgcn_mfma_f32_16x16x32_bf16(af, bf, acc[nt], 0, 0, 0);
    }
  }

  // stage 64 y-rows into LDS (coalesced 16B loads)
#pragma unroll
  for (int k2 = 0; k2 < 4; ++k2) {
    int flat = t + k2 * 256;
    int row = flat >> 4, c8 = flat & 15;
    bf16x8 vv = *(const bf16x8*)(Yb + (size_t)lrow[row] * 128 + c8 * 8);
    *(bf16x8*)(vb16 + row * 136 + c8 * 8) = vv;
  }
  __syncthreads();

  float yv[4][8];
#pragma unroll
  for (int q = 0; q < 4; ++q) {
    int r = w * 16 + g * 4 + q;
#pragma unroll
    for (int nt = 0; nt < 8; ++nt)
      yv[q][nt] = (float)vb16[r * 136 + nt * 16 + c];
  }
#pragma unroll
  for (int q = 0; q < 4; ++q) {
    int r = w * 16 + g * 4 + q;
#pragma unroll
    for (int nt = 0; nt < 8; ++nt)
      vb16[r * 136 + nt * 16 + c] = (__bf16)fmaxf(acc[nt][q] + yv[q][nt], 0.f);
  }
  __syncthreads();

#pragma unroll
  for (int k2 = 0; k2 < 4; ++k2) {
    int flat = t + k2 * 256;
    int row = flat >> 4, c8 = flat & 15;
    bf16x8 vv = *(const bf16x8*)(vb16 + row * 136 + c8 * 8);
    *(bf16x8*)(TMP + (size_t)lpos[row] * 128 + c8 * 8) = vv;
  }
}

// ======================= R: streaming segment mean ==========================
__global__ __launch_bounds__(256) void node_R(
    const __bf16* __restrict__ TMP, const int* __restrict__ cnt,
    const int* __restrict__ offs, __bf16* __restrict__ meanb)
{
  int node = blockIdx.x * 4 + (threadIdx.x >> 6);
  int lane = threadIdx.x & 63;
  int m = cnt[node];
  int start = offs[node] - m;
  float s0 = 0.f, s1 = 0.f;
  const __bf16* base = TMP + (size_t)start * 128 + lane * 2;
#pragma unroll 4
  for (int j = 0; j < m; ++j) {
    unsigned uu = *(const unsigned*)(base + (size_t)j * 128);
    s0 += __builtin_bit_cast(float, uu << 16);
    s1 += __builtin_bit_cast(float, uu & 0xffff0000u);
  }
  float inv = 1.f / fmaxf((float)m, 1.f);
  s0 *= inv; s1 *= inv;
  unsigned r0 = (unsigned)__builtin_bit_cast(unsigned short, (__bf16)s0);
  unsigned r1 = (unsigned)__builtin_bit_cast(unsigned short, (__bf16)s1);
  *(unsigned*)(meanb + (size_t)node * 128 + lane * 2) = r0 | (r1 << 16);
}

// ======================= fused h1 + out GEMM ================================
// acc  = x@WT2c + mean@WT2d (+bias/gate/vtab, relu) -> LDS (per-wave 16x128)
// acc2 = h1@WT2bT + b2b -> d_out (f32)
__global__ __launch_bounds__(256) void mlp_h1out(
    const float* __restrict__ x, const __bf16* __restrict__ meanb,
    const __bf16* __restrict__ WT2c, const __bf16* __restrict__ WT2d,
    const __bf16* __restrict__ WT2bT,
    const int* __restrict__ cnt, const float* __restrict__ b2a,
    const float* __restrict__ bc, const float* __restrict__ vtab,
    const int* __restrict__ batch, const float* __restrict__ b2b,
    float* __restrict__ out)
{
  __shared__ __bf16 ht[64 * 136];
  int lane = threadIdx.x & 63;
  int w = threadIdx.x >> 6;
  int rowbase = blockIdx.x * 64 + w * 16;
  int g = lane >> 4, c = lane & 15;

  f32x4v acc[8];
#pragma unroll
  for (int nt = 0; nt < 8; ++nt) acc[nt] = (f32x4v)(0.f);

  const float* arow = x + (size_t)(rowbase + c) * 128;
#pragma unroll
  for (int kk = 0; kk < 128; kk += 32) {
    bf16x8 af = cvt8(arow + kk + g * 8);
#pragma unroll
    for (int nt = 0; nt < 8; ++nt) {
      bf16x8 bf = *(const bf16x8*)(WT2c + (nt * 16 + c) * 128 + kk + g * 8);
      acc[nt] = __builtin_amdgcn_mfma_f32_16x16x32_bf16(af, bf, acc[nt], 0, 0, 0);
    }
  }
  const __bf16* arow2 = meanb + (size_t)(rowbase + c) * 128;
#pragma unroll
  for (int kk = 0; kk < 128; kk += 32) {
    bf16x8 af = *(const bf16x8*)(arow2 + kk + g * 8);
#pragma unroll
    for (int nt = 0; nt < 8; ++nt) {
      bf16x8 bf = *(const bf16x8*)(WT2d + (nt * 16 + c) * 128 + kk + g * 8);
      acc[nt] = __builtin_amdgcn_mfma_f32_16x16x32_bf16(af, bf, acc[nt], 0, 0, 0);
    }
  }

  // epilogue 1: h1 = relu(acc + b2a + gate*bc + vtab[batch]) -> LDS bf16
#pragma unroll
  for (int q = 0; q < 4; ++q) {
    int r = rowbase + g * 4 + q;
    float gmul = cnt[r] ? 1.f : 0.f;
    const float* vrow = vtab + (size_t)batch[r] * 128;
#pragma unroll
    for (int nt = 0; nt < 8; ++nt) {
      int n = nt * 16 + c;
      float v = acc[nt][q] + b2a[n] + gmul * bc[n] + vrow[n];
      ht[(w * 16 + g * 4 + q) * 136 + n] = (__bf16)fmaxf(v, 0.f);
    }
  }
  __syncthreads();

  // phase 2: out = h1 @ WT2bT^T + b2b
  f32x4v acc2[8];
#pragma unroll
  for (int nt = 0; nt < 8; ++nt) acc2[nt] = (f32x4v)(0.f);

  const __bf16* hrow = ht + (w * 16 + c) * 136;
#pragma unroll
  for (int kk = 0; kk < 128; kk += 32) {
    bf16x8 af = *(const bf16x8*)(hrow + kk + g * 8);
#pragma unroll
    for (int nt = 0; nt < 8; ++nt) {
      bf16x8 bf = *(const bf16x8*)(WT2bT + (nt * 16 + c) * 128 + kk + g * 8);
      acc2[nt] = __builtin_amdgcn_mfma_f32_16x16x32_bf16(af, bf, acc2[nt], 0, 0, 0);
    }
  }
#pragma unroll
  for (int q = 0; q < 4; ++q) {
    int r = rowbase + g * 4 + q;
#pragma unroll
    for (int nt = 0; nt < 8; ++nt) {
      int n = nt * 16 + c;
      out[(size_t)r * 128 + n] = acc2[nt][q] + b2b[n];
    }
  }
}

// ======================= host ===============================================
extern "C" void kernel_launch(void* const* d_in, const int* in_sizes, int n_in,
                              void* d_out, int out_size, void* d_ws, size_t ws_size,
                              hipStream_t stream) {
  const float* x    = (const float*)d_in[0];
  const int*   ei   = (const int*)d_in[1];
  const float* ea   = (const float*)d_in[2];
  const float* u    = (const float*)d_in[3];
  const int*   batch= (const int*)d_in[4];
  const float* W1a  = (const float*)d_in[5];
  const float* b1a  = (const float*)d_in[6];
  const float* W1b  = (const float*)d_in[7];
  const float* b1b  = (const float*)d_in[8];
  const float* W2a  = (const float*)d_in[9];
  const float* b2a  = (const float*)d_in[10];
  const float* W2b  = (const float*)d_in[11];
  const float* b2b  = (const float*)d_in[12];

  char* ws = (char*)d_ws;
  __bf16* WTya  = (__bf16*)(ws);              // 32768
  __bf16* WTeb  = (__bf16*)(ws + 32768);      // 16384
  __bf16* WT2c  = (__bf16*)(ws + 49152);      // 32768
  __bf16* WT2bT = (__bf16*)(ws + 81920);      // 32768
  __bf16* WT2d  = (__bf16*)(ws + 114688);     // 32768
  float*  vtab  = (float*)(ws + 147456);      // 32768
  float*  bc    = (float*)(ws + 180224);      // 512
  int*    cnt   = (int*)(ws + 180736);        // 160,000
  int*    offs  = (int*)(ws + 340736);        // 160,000
  int*    bsum  = (int*)(ws + 500736);        // 1,024
  int*    pose  = (int*)(ws + 501760);        // 2,560,000
  __bf16* Yb    = (__bf16*)(ws + 3061760);    // 10,240,000 (then meanb)
  __bf16* TMP   = (__bf16*)(ws + 13301760);   // 163,840,000 -> end 177.1 MB
  __bf16* meanb = Yb;

  // --- 1 launch: prep + zero + hist + scan + scatter (cooperative) ---------
  {
    const float *a0 = W1a, *a1 = W2a, *a2 = W2b, *a3 = W1b, *a4 = b1b, *a5 = u;
    const int* a6 = ei;
    __bf16 *a7 = WTya, *a8 = WTeb, *a9 = WT2c, *a10 = WT2bT, *a11 = WT2d;
    float *a12 = vtab, *a13 = bc;
    int *a14 = cnt, *a15 = offs, *a16 = bsum, *a17 = pose;
    void* kargs[] = {&a0,&a1,&a2,&a3,&a4,&a5,&a6,&a7,&a8,&a9,&a10,&a11,&a12,
                     &a13,&a14,&a15,&a16,&a17};
    int occ = 0;
    hipError_t oe = hipOccupancyMaxActiveBlocksPerMultiprocessor(
        &occ, (const void*)coop_prep_sort, 256, 0);
    if (oe != hipSuccess || occ < 1) occ = 1;
    int grid = occ * 256;                 // 256 CUs on MI355X
    if (grid > 2048) grid = 2048;
    if (grid < 256) grid = 256;
    hipError_t cerr = hipLaunchCooperativeKernel(
        (const void*)coop_prep_sort, dim3(grid), dim3(256), kargs, 0, stream);
    if (cerr != hipSuccess) {
      // fallback: classic 5-launch pipeline (proven in rounds 4-5)
      hipMemsetAsync(cnt, 0, 160000, stream);
      fb_prep<<<385, 256, 0, stream>>>(W1a, W2a, W2b, W1b, b1b, u,
                                       WTya, WTeb, WT2c, WT2bT, WT2d, vtab, bc);
      fb_hist<<<2500, 256, 0, stream>>>(ei, cnt);
      fb_scan<<<1, 1024, 0, stream>>>(cnt, offs);
      fb_scatter<<<2500, 256, 0, stream>>>(ei, offs, pose);
    }
  }

  gemm_y<<<625, 256, 0, stream>>>(x, WTya, b1a, Yb);
  edge_E<<<NE / 64, 256, 0, stream>>>(ea, ei, pose, WTeb, Yb, TMP);
  node_R<<<NN / 4, 256, 0, stream>>>(TMP, cnt, offs, meanb);
  mlp_h1out<<<625, 256, 0, stream>>>(x, meanb, WT2c, WT2d, WT2bT,
                                     cnt, b2a, bc, vtab, batch, b2b,
                                     (float*)d_out);
}

// Round 7
// 262.729 us; speedup vs baseline: 4.5169x; 4.5169x over previous
//
#include <hip/hip_runtime.h>
#include <hip/hip_bf16.h>

// NodeModel fused GNN block, round 7.
// Proven compute kernels (rounds 5-6) + cheap sort chain (NO grid.sync —
// round 6 showed ROCm grid.sync costs ~150us/sync at 2048 blocks):
//   memset cnt
//   prep_hist : weight transposes/folds (blocks 0..384) + histogram (385..2884)
//   scanA     : 157-block local exclusive scan + block sums
//   scanBC    : each block rescans the 157 sums in LDS, adds base
//   gemm_y    : Yb = bf16(x @ W1a_top + b1a)
//   edge_E    : TMP[atomic slot] = bf16(relu(y[row_e] + EA[e]@W1a_bot))
//               (scatter fused: offs -> END offsets, node_R contract)
//   node_R    : mean = contiguous segment sum / max(cnt,1)
//   mlp_h1out : out = relu(x@W2c + mean@W2d + b2a + gate*bc + vtab[batch]) @ W2b + b2b

typedef __bf16 bf16x8 __attribute__((ext_vector_type(8)));
typedef float f32x4v __attribute__((ext_vector_type(4)));

#define NN 40000
#define NE 640000

__device__ inline bf16x8 cvt8(const float* __restrict__ p) {
  f32x4v a = *(const f32x4v*)p;
  f32x4v b = *(const f32x4v*)(p + 4);
  bf16x8 r;
  r[0] = (__bf16)a[0]; r[1] = (__bf16)a[1]; r[2] = (__bf16)a[2]; r[3] = (__bf16)a[3];
  r[4] = (__bf16)b[0]; r[5] = (__bf16)b[1]; r[6] = (__bf16)b[2]; r[7] = (__bf16)b[3];
  return r;
}

// ================= prep (blocks 0..384) + histogram (385..2884) =============
__global__ __launch_bounds__(256) void prep_hist(
    const float* __restrict__ W1a, const float* __restrict__ W2a,
    const float* __restrict__ W2b, const float* __restrict__ W1b,
    const float* __restrict__ b1b, const float* __restrict__ u,
    const int* __restrict__ EI,
    __bf16* __restrict__ WTya, __bf16* __restrict__ WTeb,
    __bf16* __restrict__ WT2c, __bf16* __restrict__ WT2bT,
    __bf16* __restrict__ WT2d, float* __restrict__ vtab,
    float* __restrict__ bc, int* __restrict__ cnt)
{
  int b = blockIdx.x, t = threadIdx.x;
  if (b >= 385) {                     // histogram: 2500 blocks cover NE
    int e = (b - 385) * 256 + t;
    atomicAdd(&cnt[EI[NE + e]], 1);
    return;
  }
  if (b < 64) {
    int idx = b * 256 + t; int n = idx & 127; int k = idx >> 7;
    WTya[n * 128 + k] = (__bf16)W1a[k * 128 + n];
  } else if (b < 96) {
    int idx = (b - 64) * 256 + t; int n = idx & 127; int k = idx >> 7;
    WTeb[n * 64 + k] = (__bf16)W1a[(128 + k) * 128 + n];
  } else if (b < 160) {
    int idx = (b - 96) * 256 + t; int n = idx & 127; int k = idx >> 7;
    WT2c[n * 128 + k] = (__bf16)W2a[k * 128 + n];
  } else if (b < 224) {
    int idx = (b - 160) * 256 + t; int n = idx & 127; int k = idx >> 7;
    WT2bT[n * 128 + k] = (__bf16)W2b[k * 128 + n];
  } else if (b < 256) {
    int idx = (b - 224) * 256 + t; int n = idx & 127; int gi = idx >> 7;
    float s = 0.f;
    for (int k = 0; k < 64; ++k) s += u[gi * 64 + k] * W2a[(256 + k) * 128 + n];
    vtab[gi * 128 + n] = s;
  } else if (b == 256) {
    if (t < 128) {
      float s = 0.f;
      for (int j = 0; j < 128; ++j) s += b1b[j] * W2a[(128 + j) * 128 + t];
      bc[t] = s;
    }
  } else {
    int k = b - 257;
    if (t < 128) {
      float s = 0.f;
      for (int j = 0; j < 128; ++j) s += W1b[k * 128 + j] * W2a[(128 + j) * 128 + t];
      WT2d[t * 128 + k] = (__bf16)s;
    }
  }
}

// ================= parallel scan: A (block-local) + BC (add base) ===========
__global__ __launch_bounds__(256) void scanA(const int* __restrict__ cnt,
                                             int* __restrict__ offs,
                                             int* __restrict__ bsum) {
  __shared__ int sc[256];
  int i = blockIdx.x * 256 + threadIdx.x;
  int v = (i < NN) ? cnt[i] : 0;
  sc[threadIdx.x] = v;
  __syncthreads();
  for (int off = 1; off < 256; off <<= 1) {
    int t2 = (threadIdx.x >= off) ? sc[threadIdx.x - off] : 0;
    __syncthreads();
    sc[threadIdx.x] += t2;
    __syncthreads();
  }
  if (i < NN) offs[i] = sc[threadIdx.x] - v;      // exclusive within block
  if (threadIdx.x == 255) bsum[blockIdx.x] = sc[255];
}

__global__ __launch_bounds__(256) void scanBC(int* __restrict__ offs,
                                              const int* __restrict__ bsum) {
  __shared__ int sc[256];
  int t = threadIdx.x;
  sc[t] = (t < 157) ? bsum[t] : 0;
  __syncthreads();
  for (int off = 1; off < 256; off <<= 1) {
    int t2 = (t >= off) ? sc[t - off] : 0;
    __syncthreads();
    sc[t] += t2;
    __syncthreads();
  }
  int base = (blockIdx.x > 0) ? sc[blockIdx.x - 1] : 0;   // inclusive -> excl
  int i = blockIdx.x * 256 + t;
  if (i < NN) offs[i] += base;
}

// ================= y-GEMM: Yb = bf16(x @ WTya^T + b1a) ======================
__global__ __launch_bounds__(256) void gemm_y(
    const float* __restrict__ x, const __bf16* __restrict__ WTya,
    const float* __restrict__ b1a, __bf16* __restrict__ Yb)
{
  int lane = threadIdx.x & 63;
  int wave = threadIdx.x >> 6;
  int rowbase = blockIdx.x * 64 + wave * 16;
  int g = lane >> 4, c = lane & 15;

  f32x4v acc[8];
#pragma unroll
  for (int nt = 0; nt < 8; ++nt) acc[nt] = (f32x4v)(0.f);

  const float* arow = x + (size_t)(rowbase + c) * 128;
#pragma unroll
  for (int kk = 0; kk < 128; kk += 32) {
    bf16x8 af = cvt8(arow + kk + g * 8);
#pragma unroll
    for (int nt = 0; nt < 8; ++nt) {
      bf16x8 bf = *(const bf16x8*)(WTya + (nt * 16 + c) * 128 + kk + g * 8);
      acc[nt] = __builtin_amdgcn_mfma_f32_16x16x32_bf16(af, bf, acc[nt], 0, 0, 0);
    }
  }
#pragma unroll
  for (int q = 0; q < 4; ++q) {
    int r = rowbase + g * 4 + q;
#pragma unroll
    for (int nt = 0; nt < 8; ++nt) {
      int n = nt * 16 + c;
      Yb[(size_t)r * 128 + n] = (__bf16)(acc[nt][q] + b1a[n]);
    }
  }
}

// ================= E: edge GEMM + fused scatter slot alloc ==================
__global__ __launch_bounds__(256) void edge_E(
    const float* __restrict__ EA, const int* __restrict__ EI,
    int* __restrict__ offs,              // mutates to END offsets
    const __bf16* __restrict__ WTeb,
    const __bf16* __restrict__ Yb, __bf16* __restrict__ TMP)
{
  __shared__ __bf16 vb16[64 * 136];
  __shared__ int lrow[64], lpos[64];
  int t = threadIdx.x;
  int i0 = blockIdx.x * 64;
  if (t < 64) {
    lrow[t] = EI[i0 + t];
    int col = EI[NE + i0 + t];
    lpos[t] = atomicAdd(&offs[col], 1);   // fused scatter
  }
  __syncthreads();

  int lane = t & 63, w = t >> 6, g = lane >> 4, c = lane & 15;
  f32x4v acc[8];
#pragma unroll
  for (int nt = 0; nt < 8; ++nt) acc[nt] = (f32x4v)(0.f);

  const float* arow = EA + (size_t)(i0 + w * 16 + c) * 64;
#pragma unroll
  for (int kk = 0; kk < 64; kk += 32) {
    bf16x8 af = cvt8(arow + kk + g * 8);
#pragma unroll
    for (int nt = 0; nt < 8; ++nt) {
      bf16x8 bf = *(const bf16x8*)(WTeb + (nt * 16 + c) * 64 + kk + g * 8);
      acc[nt] = __builtin_amdgcn_mfma_f32_16x16x32_bf16(af, bf, acc[nt], 0, 0, 0);
    }
  }

  // stage 64 y-rows into LDS (coalesced 16B loads)
#pragma unroll
  for (int k2 = 0; k2 < 4; ++k2) {
    int flat = t + k2 * 256;
    int row = flat >> 4, c8 = flat & 15;
    bf16x8 vv = *(const bf16x8*)(Yb + (size_t)lrow[row] * 128 + c8 * 8);
    *(bf16x8*)(vb16 + row * 136 + c8 * 8) = vv;
  }
  __syncthreads();

  float yv[4][8];
#pragma unroll
  for (int q = 0; q < 4; ++q) {
    int r = w * 16 + g * 4 + q;
#pragma unroll
    for (int nt = 0; nt < 8; ++nt)
      yv[q][nt] = (float)vb16[r * 136 + nt * 16 + c];
  }
#pragma unroll
  for (int q = 0; q < 4; ++q) {
    int r = w * 16 + g * 4 + q;
#pragma unroll
    for (int nt = 0; nt < 8; ++nt)
      vb16[r * 136 + nt * 16 + c] = (__bf16)fmaxf(acc[nt][q] + yv[q][nt], 0.f);
  }
  __syncthreads();

  // scattered 256B-row stores to the allocated sorted slots
#pragma unroll
  for (int k2 = 0; k2 < 4; ++k2) {
    int flat = t + k2 * 256;
    int row = flat >> 4, c8 = flat & 15;
    bf16x8 vv = *(const bf16x8*)(vb16 + row * 136 + c8 * 8);
    *(bf16x8*)(TMP + (size_t)lpos[row] * 128 + c8 * 8) = vv;
  }
}

// ================= R: streaming segment mean ================================
__global__ __launch_bounds__(256) void node_R(
    const __bf16* __restrict__ TMP, const int* __restrict__ cnt,
    const int* __restrict__ offs, __bf16* __restrict__ meanb)
{
  int node = blockIdx.x * 4 + (threadIdx.x >> 6);
  int lane = threadIdx.x & 63;
  int m = cnt[node];
  int start = offs[node] - m;        // offs holds END offsets after edge_E
  float s0 = 0.f, s1 = 0.f;
  const __bf16* base = TMP + (size_t)start * 128 + lane * 2;
#pragma unroll 4
  for (int j = 0; j < m; ++j) {
    unsigned uu = *(const unsigned*)(base + (size_t)j * 128);
    s0 += __builtin_bit_cast(float, uu << 16);
    s1 += __builtin_bit_cast(float, uu & 0xffff0000u);
  }
  float inv = 1.f / fmaxf((float)m, 1.f);
  s0 *= inv; s1 *= inv;
  unsigned r0 = (unsigned)__builtin_bit_cast(unsigned short, (__bf16)s0);
  unsigned r1 = (unsigned)__builtin_bit_cast(unsigned short, (__bf16)s1);
  *(unsigned*)(meanb + (size_t)node * 128 + lane * 2) = r0 | (r1 << 16);
}

// ================= fused h1 + out GEMM ======================================
__global__ __launch_bounds__(256) void mlp_h1out(
    const float* __restrict__ x, const __bf16* __restrict__ meanb,
    const __bf16* __restrict__ WT2c, const __bf16* __restrict__ WT2d,
    const __bf16* __restrict__ WT2bT,
    const int* __restrict__ cnt, const float* __restrict__ b2a,
    const float* __restrict__ bc, const float* __restrict__ vtab,
    const int* __restrict__ batch, const float* __restrict__ b2b,
    float* __restrict__ out)
{
  __shared__ __bf16 ht[64 * 136];
  int lane = threadIdx.x & 63;
  int w = threadIdx.x >> 6;
  int rowbase = blockIdx.x * 64 + w * 16;
  int g = lane >> 4, c = lane & 15;

  f32x4v acc[8];
#pragma unroll
  for (int nt = 0; nt < 8; ++nt) acc[nt] = (f32x4v)(0.f);

  const float* arow = x + (size_t)(rowbase + c) * 128;
#pragma unroll
  for (int kk = 0; kk < 128; kk += 32) {
    bf16x8 af = cvt8(arow + kk + g * 8);
#pragma unroll
    for (int nt = 0; nt < 8; ++nt) {
      bf16x8 bf = *(const bf16x8*)(WT2c + (nt * 16 + c) * 128 + kk + g * 8);
      acc[nt] = __builtin_amdgcn_mfma_f32_16x16x32_bf16(af, bf, acc[nt], 0, 0, 0);
    }
  }
  const __bf16* arow2 = meanb + (size_t)(rowbase + c) * 128;
#pragma unroll
  for (int kk = 0; kk < 128; kk += 32) {
    bf16x8 af = *(const bf16x8*)(arow2 + kk + g * 8);
#pragma unroll
    for (int nt = 0; nt < 8; ++nt) {
      bf16x8 bf = *(const bf16x8*)(WT2d + (nt * 16 + c) * 128 + kk + g * 8);
      acc[nt] = __builtin_amdgcn_mfma_f32_16x16x32_bf16(af, bf, acc[nt], 0, 0, 0);
    }
  }

  // epilogue 1: h1 = relu(acc + b2a + gate*bc + vtab[batch]) -> LDS bf16
#pragma unroll
  for (int q = 0; q < 4; ++q) {
    int r = rowbase + g * 4 + q;
    float gmul = cnt[r] ? 1.f : 0.f;
    const float* vrow = vtab + (size_t)batch[r] * 128;
#pragma unroll
    for (int nt = 0; nt < 8; ++nt) {
      int n = nt * 16 + c;
      float v = acc[nt][q] + b2a[n] + gmul * bc[n] + vrow[n];
      ht[(w * 16 + g * 4 + q) * 136 + n] = (__bf16)fmaxf(v, 0.f);
    }
  }
  __syncthreads();

  // phase 2: out = h1 @ WT2bT^T + b2b
  f32x4v acc2[8];
#pragma unroll
  for (int nt = 0; nt < 8; ++nt) acc2[nt] = (f32x4v)(0.f);

  const __bf16* hrow = ht + (w * 16 + c) * 136;
#pragma unroll
  for (int kk = 0; kk < 128; kk += 32) {
    bf16x8 af = *(const bf16x8*)(hrow + kk + g * 8);
#pragma unroll
    for (int nt = 0; nt < 8; ++nt) {
      bf16x8 bf = *(const bf16x8*)(WT2bT + (nt * 16 + c) * 128 + kk + g * 8);
      acc2[nt] = __builtin_amdgcn_mfma_f32_16x16x32_bf16(af, bf, acc2[nt], 0, 0, 0);
    }
  }
#pragma unroll
  for (int q = 0; q < 4; ++q) {
    int r = rowbase + g * 4 + q;
#pragma unroll
    for (int nt = 0; nt < 8; ++nt) {
      int n = nt * 16 + c;
      out[(size_t)r * 128 + n] = acc2[nt][q] + b2b[n];
    }
  }
}

// ================= host =====================================================
extern "C" void kernel_launch(void* const* d_in, const int* in_sizes, int n_in,
                              void* d_out, int out_size, void* d_ws, size_t ws_size,
                              hipStream_t stream) {
  const float* x    = (const float*)d_in[0];
  const int*   ei   = (const int*)d_in[1];
  const float* ea   = (const float*)d_in[2];
  const float* u    = (const float*)d_in[3];
  const int*   batch= (const int*)d_in[4];
  const float* W1a  = (const float*)d_in[5];
  const float* b1a  = (const float*)d_in[6];
  const float* W1b  = (const float*)d_in[7];
  const float* b1b  = (const float*)d_in[8];
  const float* W2a  = (const float*)d_in[9];
  const float* b2a  = (const float*)d_in[10];
  const float* W2b  = (const float*)d_in[11];
  const float* b2b  = (const float*)d_in[12];

  char* ws = (char*)d_ws;
  __bf16* WTya  = (__bf16*)(ws);              // 32768
  __bf16* WTeb  = (__bf16*)(ws + 32768);      // 16384
  __bf16* WT2c  = (__bf16*)(ws + 49152);      // 32768
  __bf16* WT2bT = (__bf16*)(ws + 81920);      // 32768
  __bf16* WT2d  = (__bf16*)(ws + 114688);     // 32768
  float*  vtab  = (float*)(ws + 147456);      // 32768
  float*  bc    = (float*)(ws + 180224);      // 512
  int*    cnt   = (int*)(ws + 180736);        // 160,000
  int*    offs  = (int*)(ws + 340736);        // 160,000
  int*    bsum  = (int*)(ws + 500736);        // 1,024
  __bf16* Yb    = (__bf16*)(ws + 3061760);    // 10,240,000 (then meanb)
  __bf16* TMP   = (__bf16*)(ws + 13301760);   // 163,840,000 -> end 177.1 MB
  __bf16* meanb = Yb;

  hipMemsetAsync(cnt, 0, 160000, stream);
  prep_hist<<<2885, 256, 0, stream>>>(W1a, W2a, W2b, W1b, b1b, u, ei,
                                      WTya, WTeb, WT2c, WT2bT, WT2d,
                                      vtab, bc, cnt);
  scanA<<<157, 256, 0, stream>>>(cnt, offs, bsum);
  scanBC<<<157, 256, 0, stream>>>(offs, bsum);
  gemm_y<<<625, 256, 0, stream>>>(x, WTya, b1a, Yb);
  edge_E<<<NE / 64, 256, 0, stream>>>(ea, ei, offs, WTeb, Yb, TMP);
  node_R<<<NN / 4, 256, 0, stream>>>(TMP, cnt, offs, meanb);
  mlp_h1out<<<625, 256, 0, stream>>>(x, meanb, WT2c, WT2d, WT2bT,
                                     cnt, b2a, bc, vtab, batch, b2b,
                                     (float*)d_out);
}

// Round 8
// 248.079 us; speedup vs baseline: 4.7837x; 1.0591x over previous
//
#include <hip/hip_runtime.h>
#include <hip/hip_bf16.h>

// NodeModel fused GNN block, round 8 = round 7 + fp8-e4m3 TMP.
//   memset cnt
//   prep_hist : weight transposes/folds (blocks 0..384) + histogram (385..2884)
//   scanA/scanBC : two-kernel parallel exclusive scan of cnt -> offs
//   gemm_y    : Yb = bf16(x @ W1a_top + b1a)
//   edge_E    : TMP8[atomic slot] = fp8(relu(y[row_e] + EA[e]@W1a_bot))
//               (scatter fused into E; offs -> END offsets)
//   node_R    : mean = contiguous fp8 segment sum / max(cnt,1)  (2 rows/iter)
//   mlp_h1out : out = relu(x@W2c + mean@W2d + b2a + gate*bc + vtab[batch]) @ W2b + b2b
// TMP fp8 halves the scattered-write + re-read traffic (328 -> 164 MB);
// encode/decode via gfx950 HW v_cvt_pk_fp8_f32 / v_cvt_pk_f32_fp8 (OCP e4m3).

typedef __bf16 bf16x8 __attribute__((ext_vector_type(8)));
typedef float f32x4v __attribute__((ext_vector_type(4)));
typedef float f32x2v __attribute__((ext_vector_type(2)));
typedef unsigned int u32x2v __attribute__((ext_vector_type(2)));
typedef unsigned int u32x4v __attribute__((ext_vector_type(4)));

#define NN 40000
#define NE 640000

__device__ inline bf16x8 cvt8(const float* __restrict__ p) {
  f32x4v a = *(const f32x4v*)p;
  f32x4v b = *(const f32x4v*)(p + 4);
  bf16x8 r;
  r[0] = (__bf16)a[0]; r[1] = (__bf16)a[1]; r[2] = (__bf16)a[2]; r[3] = (__bf16)a[3];
  r[4] = (__bf16)b[0]; r[5] = (__bf16)b[1]; r[6] = (__bf16)b[2]; r[7] = (__bf16)b[3];
  return r;
}

// bf16 pair (packed in u32) -> two f32
__device__ inline float blo(unsigned u) { return __builtin_bit_cast(float, u << 16); }
__device__ inline float bhi(unsigned u) { return __builtin_bit_cast(float, u & 0xffff0000u); }

// ================= prep (blocks 0..384) + histogram (385..2884) =============
__global__ __launch_bounds__(256) void prep_hist(
    const float* __restrict__ W1a, const float* __restrict__ W2a,
    const float* __restrict__ W2b, const float* __restrict__ W1b,
    const float* __restrict__ b1b, const float* __restrict__ u,
    const int* __restrict__ EI,
    __bf16* __restrict__ WTya, __bf16* __restrict__ WTeb,
    __bf16* __restrict__ WT2c, __bf16* __restrict__ WT2bT,
    __bf16* __restrict__ WT2d, float* __restrict__ vtab,
    float* __restrict__ bc, int* __restrict__ cnt)
{
  int b = blockIdx.x, t = threadIdx.x;
  if (b >= 385) {                     // histogram: 2500 blocks cover NE
    int e = (b - 385) * 256 + t;
    atomicAdd(&cnt[EI[NE + e]], 1);
    return;
  }
  if (b < 64) {
    int idx = b * 256 + t; int n = idx & 127; int k = idx >> 7;
    WTya[n * 128 + k] = (__bf16)W1a[k * 128 + n];
  } else if (b < 96) {
    int idx = (b - 64) * 256 + t; int n = idx & 127; int k = idx >> 7;
    WTeb[n * 64 + k] = (__bf16)W1a[(128 + k) * 128 + n];
  } else if (b < 160) {
    int idx = (b - 96) * 256 + t; int n = idx & 127; int k = idx >> 7;
    WT2c[n * 128 + k] = (__bf16)W2a[k * 128 + n];
  } else if (b < 224) {
    int idx = (b - 160) * 256 + t; int n = idx & 127; int k = idx >> 7;
    WT2bT[n * 128 + k] = (__bf16)W2b[k * 128 + n];
  } else if (b < 256) {
    int idx = (b - 224) * 256 + t; int n = idx & 127; int gi = idx >> 7;
    float s = 0.f;
    for (int k = 0; k < 64; ++k) s += u[gi * 64 + k] * W2a[(256 + k) * 128 + n];
    vtab[gi * 128 + n] = s;
  } else if (b == 256) {
    if (t < 128) {
      float s = 0.f;
      for (int j = 0; j < 128; ++j) s += b1b[j] * W2a[(128 + j) * 128 + t];
      bc[t] = s;
    }
  } else {
    int k = b - 257;
    if (t < 128) {
      float s = 0.f;
      for (int j = 0; j < 128; ++j) s += W1b[k * 128 + j] * W2a[(128 + j) * 128 + t];
      WT2d[t * 128 + k] = (__bf16)s;
    }
  }
}

// ================= parallel scan: A (block-local) + BC (add base) ===========
__global__ __launch_bounds__(256) void scanA(const int* __restrict__ cnt,
                                             int* __restrict__ offs,
                                             int* __restrict__ bsum) {
  __shared__ int sc[256];
  int i = blockIdx.x * 256 + threadIdx.x;
  int v = (i < NN) ? cnt[i] : 0;
  sc[threadIdx.x] = v;
  __syncthreads();
  for (int off = 1; off < 256; off <<= 1) {
    int t2 = (threadIdx.x >= off) ? sc[threadIdx.x - off] : 0;
    __syncthreads();
    sc[threadIdx.x] += t2;
    __syncthreads();
  }
  if (i < NN) offs[i] = sc[threadIdx.x] - v;      // exclusive within block
  if (threadIdx.x == 255) bsum[blockIdx.x] = sc[255];
}

__global__ __launch_bounds__(256) void scanBC(int* __restrict__ offs,
                                              const int* __restrict__ bsum) {
  __shared__ int sc[256];
  int t = threadIdx.x;
  sc[t] = (t < 157) ? bsum[t] : 0;
  __syncthreads();
  for (int off = 1; off < 256; off <<= 1) {
    int t2 = (t >= off) ? sc[t - off] : 0;
    __syncthreads();
    sc[t] += t2;
    __syncthreads();
  }
  int base = (blockIdx.x > 0) ? sc[blockIdx.x - 1] : 0;   // inclusive -> excl
  int i = blockIdx.x * 256 + t;
  if (i < NN) offs[i] += base;
}

// ================= y-GEMM: Yb = bf16(x @ WTya^T + b1a) ======================
__global__ __launch_bounds__(256) void gemm_y(
    const float* __restrict__ x, const __bf16* __restrict__ WTya,
    const float* __restrict__ b1a, __bf16* __restrict__ Yb)
{
  int lane = threadIdx.x & 63;
  int wave = threadIdx.x >> 6;
  int rowbase = blockIdx.x * 64 + wave * 16;
  int g = lane >> 4, c = lane & 15;

  f32x4v acc[8];
#pragma unroll
  for (int nt = 0; nt < 8; ++nt) acc[nt] = (f32x4v)(0.f);

  const float* arow = x + (size_t)(rowbase + c) * 128;
#pragma unroll
  for (int kk = 0; kk < 128; kk += 32) {
    bf16x8 af = cvt8(arow + kk + g * 8);
#pragma unroll
    for (int nt = 0; nt < 8; ++nt) {
      bf16x8 bf = *(const bf16x8*)(WTya + (nt * 16 + c) * 128 + kk + g * 8);
      acc[nt] = __builtin_amdgcn_mfma_f32_16x16x32_bf16(af, bf, acc[nt], 0, 0, 0);
    }
  }
#pragma unroll
  for (int q = 0; q < 4; ++q) {
    int r = rowbase + g * 4 + q;
#pragma unroll
    for (int nt = 0; nt < 8; ++nt) {
      int n = nt * 16 + c;
      Yb[(size_t)r * 128 + n] = (__bf16)(acc[nt][q] + b1a[n]);
    }
  }
}

// ================= E: edge GEMM + fused scatter, fp8 scattered store ========
__global__ __launch_bounds__(256) void edge_E(
    const float* __restrict__ EA, const int* __restrict__ EI,
    int* __restrict__ offs,              // mutates to END offsets
    const __bf16* __restrict__ WTeb,
    const __bf16* __restrict__ Yb,
    unsigned char* __restrict__ TMP8)    // 640000 x 128 fp8, sorted slots
{
  __shared__ __bf16 vb16[64 * 136];
  __shared__ int lrow[64], lpos[64];
  int t = threadIdx.x;
  int i0 = blockIdx.x * 64;
  if (t < 64) {
    lrow[t] = EI[i0 + t];
    int col = EI[NE + i0 + t];
    lpos[t] = atomicAdd(&offs[col], 1);   // fused scatter
  }
  __syncthreads();

  int lane = t & 63, w = t >> 6, g = lane >> 4, c = lane & 15;
  f32x4v acc[8];
#pragma unroll
  for (int nt = 0; nt < 8; ++nt) acc[nt] = (f32x4v)(0.f);

  const float* arow = EA + (size_t)(i0 + w * 16 + c) * 64;
#pragma unroll
  for (int kk = 0; kk < 64; kk += 32) {
    bf16x8 af = cvt8(arow + kk + g * 8);
#pragma unroll
    for (int nt = 0; nt < 8; ++nt) {
      bf16x8 bf = *(const bf16x8*)(WTeb + (nt * 16 + c) * 64 + kk + g * 8);
      acc[nt] = __builtin_amdgcn_mfma_f32_16x16x32_bf16(af, bf, acc[nt], 0, 0, 0);
    }
  }

  // stage 64 y-rows into LDS (coalesced 16B loads)
#pragma unroll
  for (int k2 = 0; k2 < 4; ++k2) {
    int flat = t + k2 * 256;
    int row = flat >> 4, c8 = flat & 15;
    bf16x8 vv = *(const bf16x8*)(Yb + (size_t)lrow[row] * 128 + c8 * 8);
    *(bf16x8*)(vb16 + row * 136 + c8 * 8) = vv;
  }
  __syncthreads();

  float yv[4][8];
#pragma unroll
  for (int q = 0; q < 4; ++q) {
    int r = w * 16 + g * 4 + q;
#pragma unroll
    for (int nt = 0; nt < 8; ++nt)
      yv[q][nt] = (float)vb16[r * 136 + nt * 16 + c];
  }
#pragma unroll
  for (int q = 0; q < 4; ++q) {
    int r = w * 16 + g * 4 + q;
#pragma unroll
    for (int nt = 0; nt < 8; ++nt)
      vb16[r * 136 + nt * 16 + c] = (__bf16)fmaxf(acc[nt][q] + yv[q][nt], 0.f);
  }
  __syncthreads();

  // fp8-encode + scattered 128B-row stores: 64 rows x 8 chunks of 16 cols;
  // 512 chunks, 2 per thread. Each chunk: 32B LDS read -> 16B fp8 store.
#pragma unroll
  for (int k2 = 0; k2 < 2; ++k2) {
    int flat = t + k2 * 256;            // 0..511
    int row = flat >> 3, c16 = flat & 7;
    const __bf16* src = vb16 + row * 136 + c16 * 16;
    u32x4v a = *(const u32x4v*)src;       // cols 0..7 of chunk (bf16 pairs)
    u32x4v b = *(const u32x4v*)(src + 8); // cols 8..15
    u32x4v o;
    o[0] = __builtin_amdgcn_cvt_pk_fp8_f32(blo(a[0]), bhi(a[0]), 0, false);
    o[0] = __builtin_amdgcn_cvt_pk_fp8_f32(blo(a[1]), bhi(a[1]), o[0], true);
    o[1] = __builtin_amdgcn_cvt_pk_fp8_f32(blo(a[2]), bhi(a[2]), 0, false);
    o[1] = __builtin_amdgcn_cvt_pk_fp8_f32(blo(a[3]), bhi(a[3]), o[1], true);
    o[2] = __builtin_amdgcn_cvt_pk_fp8_f32(blo(b[0]), bhi(b[0]), 0, false);
    o[2] = __builtin_amdgcn_cvt_pk_fp8_f32(blo(b[1]), bhi(b[1]), o[2], true);
    o[3] = __builtin_amdgcn_cvt_pk_fp8_f32(blo(b[2]), bhi(b[2]), 0, false);
    o[3] = __builtin_amdgcn_cvt_pk_fp8_f32(blo(b[3]), bhi(b[3]), o[3], true);
    *(u32x4v*)(TMP8 + (size_t)lpos[row] * 128 + c16 * 16) = o;
  }
}

// ================= R: streaming fp8 segment mean (2 rows / iter) ============
__global__ __launch_bounds__(256) void node_R(
    const unsigned int* __restrict__ TMP32,   // fp8 rows as 32 x u32
    const int* __restrict__ cnt,
    const int* __restrict__ offs,             // END offsets
    __bf16* __restrict__ meanb)
{
  int node = blockIdx.x * 4 + (threadIdx.x >> 6);
  int lane = threadIdx.x & 63;
  int rowpar = lane >> 5;          // 0/1: which of the row pair
  int cu = lane & 31;              // u32 column (4 fp8 = 4 feature cols)
  int m = cnt[node];
  int start = offs[node] - m;
  float s0 = 0.f, s1 = 0.f, s2 = 0.f, s3 = 0.f;
  int iters = (m + 1) >> 1;
  for (int j = 0; j < iters; ++j) {
    int r2 = 2 * j + rowpar;
    unsigned uu = (r2 < m) ? TMP32[(size_t)(start + r2) * 32 + cu] : 0u;
    f32x2v lo = __builtin_amdgcn_cvt_pk_f32_fp8(uu, false);
    f32x2v hi = __builtin_amdgcn_cvt_pk_f32_fp8(uu, true);
    s0 += lo[0]; s1 += lo[1]; s2 += hi[0]; s3 += hi[1];
  }
  // combine row parities: lane l and l^32 hold the same columns
  s0 += __shfl_xor(s0, 32);
  s1 += __shfl_xor(s1, 32);
  s2 += __shfl_xor(s2, 32);
  s3 += __shfl_xor(s3, 32);
  if (rowpar == 0) {
    float inv = 1.f / fmaxf((float)m, 1.f);
    s0 *= inv; s1 *= inv; s2 *= inv; s3 *= inv;
    unsigned p0 = ((unsigned)__builtin_bit_cast(unsigned short, (__bf16)s0)) |
                  ((unsigned)__builtin_bit_cast(unsigned short, (__bf16)s1) << 16);
    unsigned p1 = ((unsigned)__builtin_bit_cast(unsigned short, (__bf16)s2)) |
                  ((unsigned)__builtin_bit_cast(unsigned short, (__bf16)s3) << 16);
    u32x2v pk; pk[0] = p0; pk[1] = p1;
    *(u32x2v*)(meanb + (size_t)node * 128 + cu * 4) = pk;
  }
}

// ================= fused h1 + out GEMM ======================================
__global__ __launch_bounds__(256) void mlp_h1out(
    const float* __restrict__ x, const __bf16* __restrict__ meanb,
    const __bf16* __restrict__ WT2c, const __bf16* __restrict__ WT2d,
    const __bf16* __restrict__ WT2bT,
    const int* __restrict__ cnt, const float* __restrict__ b2a,
    const float* __restrict__ bc, const float* __restrict__ vtab,
    const int* __restrict__ batch, const float* __restrict__ b2b,
    float* __restrict__ out)
{
  __shared__ __bf16 ht[64 * 136];
  int lane = threadIdx.x & 63;
  int w = threadIdx.x >> 6;
  int rowbase = blockIdx.x * 64 + w * 16;
  int g = lane >> 4, c = lane & 15;

  f32x4v acc[8];
#pragma unroll
  for (int nt = 0; nt < 8; ++nt) acc[nt] = (f32x4v)(0.f);

  const float* arow = x + (size_t)(rowbase + c) * 128;
#pragma unroll
  for (int kk = 0; kk < 128; kk += 32) {
    bf16x8 af = cvt8(arow + kk + g * 8);
#pragma unroll
    for (int nt = 0; nt < 8; ++nt) {
      bf16x8 bf = *(const bf16x8*)(WT2c + (nt * 16 + c) * 128 + kk + g * 8);
      acc[nt] = __builtin_amdgcn_mfma_f32_16x16x32_bf16(af, bf, acc[nt], 0, 0, 0);
    }
  }
  const __bf16* arow2 = meanb + (size_t)(rowbase + c) * 128;
#pragma unroll
  for (int kk = 0; kk < 128; kk += 32) {
    bf16x8 af = *(const bf16x8*)(arow2 + kk + g * 8);
#pragma unroll
    for (int nt = 0; nt < 8; ++nt) {
      bf16x8 bf = *(const bf16x8*)(WT2d + (nt * 16 + c) * 128 + kk + g * 8);
      acc[nt] = __builtin_amdgcn_mfma_f32_16x16x32_bf16(af, bf, acc[nt], 0, 0, 0);
    }
  }

  // epilogue 1: h1 = relu(acc + b2a + gate*bc + vtab[batch]) -> LDS bf16
#pragma unroll
  for (int q = 0; q < 4; ++q) {
    int r = rowbase + g * 4 + q;
    float gmul = cnt[r] ? 1.f : 0.f;
    const float* vrow = vtab + (size_t)batch[r] * 128;
#pragma unroll
    for (int nt = 0; nt < 8; ++nt) {
      int n = nt * 16 + c;
      float v = acc[nt][q] + b2a[n] + gmul * bc[n] + vrow[n];
      ht[(w * 16 + g * 4 + q) * 136 + n] = (__bf16)fmaxf(v, 0.f);
    }
  }
  __syncthreads();

  // phase 2: out = h1 @ WT2bT^T + b2b
  f32x4v acc2[8];
#pragma unroll
  for (int nt = 0; nt < 8; ++nt) acc2[nt] = (f32x4v)(0.f);

  const __bf16* hrow = ht + (w * 16 + c) * 136;
#pragma unroll
  for (int kk = 0; kk < 128; kk += 32) {
    bf16x8 af = *(const bf16x8*)(hrow + kk + g * 8);
#pragma unroll
    for (int nt = 0; nt < 8; ++nt) {
      bf16x8 bf = *(const bf16x8*)(WT2bT + (nt * 16 + c) * 128 + kk + g * 8);
      acc2[nt] = __builtin_amdgcn_mfma_f32_16x16x32_bf16(af, bf, acc2[nt], 0, 0, 0);
    }
  }
#pragma unroll
  for (int q = 0; q < 4; ++q) {
    int r = rowbase + g * 4 + q;
#pragma unroll
    for (int nt = 0; nt < 8; ++nt) {
      int n = nt * 16 + c;
      out[(size_t)r * 128 + n] = acc2[nt][q] + b2b[n];
    }
  }
}

// ================= host =====================================================
extern "C" void kernel_launch(void* const* d_in, const int* in_sizes, int n_in,
                              void* d_out, int out_size, void* d_ws, size_t ws_size,
                              hipStream_t stream) {
  const float* x    = (const float*)d_in[0];
  const int*   ei   = (const int*)d_in[1];
  const float* ea   = (const float*)d_in[2];
  const float* u    = (const float*)d_in[3];
  const int*   batch= (const int*)d_in[4];
  const float* W1a  = (const float*)d_in[5];
  const float* b1a  = (const float*)d_in[6];
  const float* W1b  = (const float*)d_in[7];
  const float* b1b  = (const float*)d_in[8];
  const float* W2a  = (const float*)d_in[9];
  const float* b2a  = (const float*)d_in[10];
  const float* W2b  = (const float*)d_in[11];
  const float* b2b  = (const float*)d_in[12];

  char* ws = (char*)d_ws;
  __bf16* WTya  = (__bf16*)(ws);              // 32768
  __bf16* WTeb  = (__bf16*)(ws + 32768);      // 16384
  __bf16* WT2c  = (__bf16*)(ws + 49152);      // 32768
  __bf16* WT2bT = (__bf16*)(ws + 81920);      // 32768
  __bf16* WT2d  = (__bf16*)(ws + 114688);     // 32768
  float*  vtab  = (float*)(ws + 147456);      // 32768
  float*  bc    = (float*)(ws + 180224);      // 512
  int*    cnt   = (int*)(ws + 180736);        // 160,000
  int*    offs  = (int*)(ws + 340736);        // 160,000
  int*    bsum  = (int*)(ws + 500736);        // 1,024
  __bf16* Yb    = (__bf16*)(ws + 3061760);    // 10,240,000 (then meanb)
  unsigned char* TMP8 = (unsigned char*)(ws + 13301760); // 81,920,000 -> 95.2 MB
  __bf16* meanb = Yb;

  hipMemsetAsync(cnt, 0, 160000, stream);
  prep_hist<<<2885, 256, 0, stream>>>(W1a, W2a, W2b, W1b, b1b, u, ei,
                                      WTya, WTeb, WT2c, WT2bT, WT2d,
                                      vtab, bc, cnt);
  scanA<<<157, 256, 0, stream>>>(cnt, offs, bsum);
  scanBC<<<157, 256, 0, stream>>>(offs, bsum);
  gemm_y<<<625, 256, 0, stream>>>(x, WTya, b1a, Yb);
  edge_E<<<NE / 64, 256, 0, stream>>>(ea, ei, offs, WTeb, Yb, TMP8);
  node_R<<<NN / 4, 256, 0, stream>>>((const unsigned int*)TMP8, cnt, offs, meanb);
  mlp_h1out<<<625, 256, 0, stream>>>(x, meanb, WT2c, WT2d, WT2bT,
                                     cnt, b2a, bc, vtab, batch, b2b,
                                     (float*)d_out);
}